// Round 4
// baseline (58.610 us; speedup 1.0000x reference)
//
#include <hip/hip_runtime.h>
#include <math.h>

#define EPSF 1e-6f

__device__ __forceinline__ float sigmoidf_(float v) { return 1.0f / (1.0f + __expf(-v)); }

// ---------------- Kernel 1: ConvDeepSet encoder (templated, packed LDS) ----------------
// grid: (ceil(M/8), nb), block 1024 (128 n-groups x 8 m). NITER = npts/128 compile-time.
template<int NITER>
__global__ __launch_bounds__(1024) void enc_kernel_t(
    const float* __restrict__ x, const float* __restrict__ y,
    const float* __restrict__ xg, const float* __restrict__ enc_sigma,
    const float* __restrict__ gW, const float* __restrict__ gb,
    float* __restrict__ rep_s, int nb, int M)
{
    constexpr int NPTS = NITER * 128;
    __shared__ float2 spk[3 * NPTS];      // [c][n] = {x, y}
    __shared__ float red[16][8][6];
    __shared__ float tot[8][6];
    int b = blockIdx.y;
    int mt = blockIdx.x * 8;
    int tid = threadIdx.x;
    // stage packed (x,y) -> per-channel SoA float2
    {
        const float4* x4 = (const float4*)(x + (size_t)b * NPTS * 3);
        const float4* y4 = (const float4*)(y + (size_t)b * NPTS * 3);
        constexpr int N4 = NPTS * 3 / 4;
        for (int i = tid; i < N4; i += 1024) {
            float4 xv = x4[i], yv = y4[i];
            int e = 4 * i;
            float vx[4] = {xv.x, xv.y, xv.z, xv.w};
            float vy[4] = {yv.x, yv.y, yv.z, yv.w};
            #pragma unroll
            for (int j = 0; j < 4; j++) {
                int ee = e + j, n = ee / 3, c = ee - n * 3;
                spk[c * NPTS + n] = make_float2(vx[j], vy[j]);
            }
        }
    }
    int mi = tid & 7, ng = tid >> 3;
    int m = mt + mi;
    bool mv = (m < M);
    float e1[3], g[3];
    for (int c = 0; c < 3; c++) {
        float inv = 1.0f / (__expf(enc_sigma[c]) + EPSF);
        e1[c] = -0.5f * inv * inv;
    }
    for (int c = 0; c < 3; c++) g[c] = mv ? xg[(size_t)(b * M + m) * 3 + c] : 0.0f;
    __syncthreads();
    float h0a[3] = {0,0,0}, h1a[3] = {0,0,0};
    float h0b[3] = {0,0,0}, h1b[3] = {0,0,0};
    #pragma unroll
    for (int it = 0; it < NITER; ++it) {
        int n = ng + (it << 7);
        #pragma unroll
        for (int c = 0; c < 3; c++) {
            float2 v = spk[c * NPTS + n];
            float d = v.x - g[c];
            float w = __expf(e1[c] * d * d);
            if (it & 1) { h0b[c] += w; h1b[c] = fmaf(v.y, w, h1b[c]); }
            else        { h0a[c] += w; h1a[c] = fmaf(v.y, w, h1a[c]); }
        }
    }
    float h0[3], h1[3];
    for (int c = 0; c < 3; c++) { h0[c] = h0a[c] + h0b[c]; h1[c] = h1a[c] + h1b[c]; }
    // butterfly over lane bits 3..5 -> sum across the 8 ng-groups in each wave
    for (int mask = 8; mask <= 32; mask <<= 1) {
        for (int c = 0; c < 3; c++) {
            h0[c] += __shfl_xor(h0[c], mask, 64);
            h1[c] += __shfl_xor(h1[c], mask, 64);
        }
    }
    int lane = tid & 63, wv = tid >> 6;
    if (lane < 8) {
        for (int c = 0; c < 3; c++) { red[wv][lane][c] = h0[c]; red[wv][lane][3 + c] = h1[c]; }
    }
    __syncthreads();
    if (tid < 48) {
        int mi2 = tid & 7, c2 = tid >> 3;
        float s = 0.0f;
        for (int k = 0; k < 16; k++) s += red[k][mi2][c2];
        tot[mi2][c2] = s;
    }
    __syncthreads();
    if (tid < 128) {
        int mi2 = tid & 7, j = tid >> 3;
        int m2 = mt + mi2;
        if (m2 < M) {
            float cat[6];
            for (int c = 0; c < 3; c++) {
                cat[c] = tot[mi2][c];
                cat[3 + c] = tot[mi2][3 + c] / (tot[mi2][c] + EPSF);
            }
            float r = gb[j];
            for (int i = 0; i < 6; i++) r = fmaf(cat[i], gW[i * 16 + j], r);
            rep_s[((size_t)b * 16 + j) * M + m2] = sigmoidf_(r);
        }
    }
}

// generic fallback (runtime npts)
__global__ __launch_bounds__(1024) void enc_kernel_g(
    const float* __restrict__ x, const float* __restrict__ y,
    const float* __restrict__ xg, const float* __restrict__ enc_sigma,
    const float* __restrict__ gW, const float* __restrict__ gb,
    float* __restrict__ rep_s, int nb, int npts, int M)
{
    __shared__ float sx[6144];
    __shared__ float sy[6144];
    __shared__ float red[16][8][6];
    __shared__ float tot[8][6];
    int b = blockIdx.y;
    int mt = blockIdx.x * 8;
    int tid = threadIdx.x;
    int n3 = npts * 3;
    for (int i = tid; i < n3; i += 1024) {
        sx[i] = x[(size_t)b * n3 + i];
        sy[i] = y[(size_t)b * n3 + i];
    }
    int mi = tid & 7, ng = tid >> 3;
    int m = mt + mi;
    bool mv = (m < M);
    float e1[3], g[3];
    for (int c = 0; c < 3; c++) {
        float inv = 1.0f / (__expf(enc_sigma[c]) + EPSF);
        e1[c] = -0.5f * inv * inv;
    }
    for (int c = 0; c < 3; c++) g[c] = mv ? xg[(size_t)(b * M + m) * 3 + c] : 0.0f;
    __syncthreads();
    float h0[3] = {0,0,0}, h1[3] = {0,0,0};
    for (int n = ng; n < npts; n += 128) {
        for (int c = 0; c < 3; c++) {
            float d = sx[n * 3 + c] - g[c];
            float w = __expf(e1[c] * d * d);
            h0[c] += w;
            h1[c] = fmaf(sy[n * 3 + c], w, h1[c]);
        }
    }
    for (int mask = 8; mask <= 32; mask <<= 1) {
        for (int c = 0; c < 3; c++) {
            h0[c] += __shfl_xor(h0[c], mask, 64);
            h1[c] += __shfl_xor(h1[c], mask, 64);
        }
    }
    int lane = tid & 63, wv = tid >> 6;
    if (lane < 8) {
        for (int c = 0; c < 3; c++) { red[wv][lane][c] = h0[c]; red[wv][lane][3 + c] = h1[c]; }
    }
    __syncthreads();
    if (tid < 48) {
        int mi2 = tid & 7, c2 = tid >> 3;
        float s = 0.0f;
        for (int k = 0; k < 16; k++) s += red[k][mi2][c2];
        tot[mi2][c2] = s;
    }
    __syncthreads();
    if (tid < 128) {
        int mi2 = tid & 7, j = tid >> 3;
        int m2 = mt + mi2;
        if (m2 < M) {
            float cat[6];
            for (int c = 0; c < 3; c++) {
                cat[c] = tot[mi2][c];
                cat[3 + c] = tot[mi2][3 + c] / (tot[mi2][c] + EPSF);
            }
            float r = gb[j];
            for (int i = 0; i < 6; i++) r = fmaf(cat[i], gW[i * 16 + j], r);
            rep_s[((size_t)b * 16 + j) * M + m2] = sigmoidf_(r);
        }
    }
}

// ---------------- Kernel 2: rho CNN (3 convs) + linear head ----------------
// grid: (ceil(M/8), nb), block 256; col tile = 8. Padded weight strides 81/161
// (bank-conflict-free), up-front float4 staging, w3 early-load (T14).
__global__ __launch_bounds__(256) void rho_kernel(
    const float* __restrict__ rep_s,
    const float* __restrict__ w1, const float* __restrict__ b1,
    const float* __restrict__ w2, const float* __restrict__ b2,
    const float* __restrict__ w3, const float* __restrict__ b3,
    const float* __restrict__ linW, const float* __restrict__ linb,
    float* __restrict__ mu, float* __restrict__ stdv,
    int nb, int M)
{
    __shared__ float sWA[5152];     // w1 padded (32*81=2592 used), later w3 (32*161=5152)
    __shared__ float sWB[5152];     // w2 padded (32*161)
    __shared__ float sIn[16][20];   // input cols t0-6 .. t0+13
    __shared__ float sH1[32][16];   // cols t0-4 .. t0+11
    __shared__ float sH2[32][12];   // cols t0-2 .. t0+9
    __shared__ float sH3[32][8];    // cols t0   .. t0+7
    int b = blockIdx.y;
    int t0 = blockIdx.x * 8;
    int tid = threadIdx.x;
    // ---- stage w1, w2 (float4 global reads, padded LDS scatter) + input tile ----
    {
        const float4* w1v = (const float4*)w1;   // 640 float4
        const float4* w2v = (const float4*)w2;   // 1280 float4
        for (int i4 = tid; i4 < 640; i4 += 256) {
            float4 v = w1v[i4];
            float vv[4] = {v.x, v.y, v.z, v.w};
            #pragma unroll
            for (int j = 0; j < 4; j++) {
                int e = 4 * i4 + j;
                sWA[(e / 80) * 81 + e % 80] = vv[j];    // w1 row (o): 16*5=80 -> stride 81
            }
        }
        for (int i4 = tid; i4 < 1280; i4 += 256) {
            float4 v = w2v[i4];
            float vv[4] = {v.x, v.y, v.z, v.w};
            #pragma unroll
            for (int j = 0; j < 4; j++) {
                int e = 4 * i4 + j;
                sWB[(e / 160) * 161 + e % 160] = vv[j];  // w2 row (o): 32*5=160 -> stride 161
            }
        }
        for (int idx = tid; idx < 16 * 20; idx += 256) {
            int i = idx / 20, q = idx % 20;
            int mg = t0 - 6 + q;
            sIn[i][q] = (mg >= 0 && mg < M) ? rep_s[((size_t)b * 16 + i) * M + mg] : 0.0f;
        }
    }
    __syncthreads();
    int o = tid >> 3, q0 = tid & 7;
    // ---- conv1: 16 out cols (global col = t0 - 4 + q), q = q0, q0+8 ----
    {
        float a0 = b1[o], a1 = a0;
        #pragma unroll
        for (int i = 0; i < 16; i++) {
            const float* wp = sWA + o * 81 + i * 5;
            float w0 = wp[0], w1r = wp[1], w2r = wp[2], w3r = wp[3], w4 = wp[4];
            const float* ip = &sIn[i][0];
            a0 = fmaf(ip[q0], w0, a0);      a0 = fmaf(ip[q0+1], w1r, a0);
            a0 = fmaf(ip[q0+2], w2r, a0);   a0 = fmaf(ip[q0+3], w3r, a0);
            a0 = fmaf(ip[q0+4], w4, a0);
            a1 = fmaf(ip[q0+8], w0, a1);    a1 = fmaf(ip[q0+9], w1r, a1);
            a1 = fmaf(ip[q0+10], w2r, a1);  a1 = fmaf(ip[q0+11], w3r, a1);
            a1 = fmaf(ip[q0+12], w4, a1);
        }
        int g0 = t0 - 4 + q0, g1 = g0 + 8;
        sH1[o][q0]     = (g0 >= 0 && g0 < M) ? fmaxf(a0, 0.0f) : 0.0f;
        sH1[o][q0 + 8] = (g1 >= 0 && g1 < M) ? fmaxf(a1, 0.0f) : 0.0f;
    }
    __syncthreads();   // conv1 (sWA) reads done; sH1 ready
    // ---- issue w3 loads early: global -> regs; LDS-write after conv2 ----
    float4 wreg[5];
    {
        const float4* w3v = (const float4*)w3;   // 1280 float4
        #pragma unroll
        for (int h = 0; h < 5; h++) wreg[h] = w3v[tid + 256 * h];
    }
    // ---- conv2: 12 out cols (global col = t0 - 2 + q), q = q0 (+ q0+8 if q0<4) ----
    {
        float a0 = b2[o], a1 = a0;
        bool second = (q0 < 4);
        #pragma unroll
        for (int i = 0; i < 32; i++) {
            const float* wp = sWB + o * 161 + i * 5;
            float w0 = wp[0], w1r = wp[1], w2r = wp[2], w3r = wp[3], w4 = wp[4];
            const float* ip = &sH1[i][0];
            a0 = fmaf(ip[q0], w0, a0);      a0 = fmaf(ip[q0+1], w1r, a0);
            a0 = fmaf(ip[q0+2], w2r, a0);   a0 = fmaf(ip[q0+3], w3r, a0);
            a0 = fmaf(ip[q0+4], w4, a0);
            if (second) {
                a1 = fmaf(ip[q0+8], w0, a1);    a1 = fmaf(ip[q0+9], w1r, a1);
                a1 = fmaf(ip[q0+10], w2r, a1);  a1 = fmaf(ip[q0+11], w3r, a1);
                a1 = fmaf(ip[q0+12], w4, a1);
            }
        }
        int g0 = t0 - 2 + q0, g1 = g0 + 8;
        sH2[o][q0] = (g0 >= 0 && g0 < M) ? fmaxf(a0, 0.0f) : 0.0f;
        if (second) sH2[o][q0 + 8] = (g1 >= 0 && g1 < M) ? fmaxf(a1, 0.0f) : 0.0f;
    }
    // write staged w3 into sWA (padded stride 161)
    #pragma unroll
    for (int h = 0; h < 5; h++) {
        float vv[4] = {wreg[h].x, wreg[h].y, wreg[h].z, wreg[h].w};
        #pragma unroll
        for (int j = 0; j < 4; j++) {
            int e = 4 * (tid + 256 * h) + j;
            sWA[(e / 160) * 161 + e % 160] = vv[j];
        }
    }
    __syncthreads();   // sH2 + w3 ready
    // ---- conv3: 8 out cols (global col = t0 + q0), no relu ----
    {
        float a0 = b3[o];
        #pragma unroll
        for (int i = 0; i < 32; i++) {
            const float* wp = sWA + o * 161 + i * 5;
            float w0 = wp[0], w1r = wp[1], w2r = wp[2], w3r = wp[3], w4 = wp[4];
            const float* ip = &sH2[i][0];
            a0 = fmaf(ip[q0], w0, a0);      a0 = fmaf(ip[q0+1], w1r, a0);
            a0 = fmaf(ip[q0+2], w2r, a0);   a0 = fmaf(ip[q0+3], w3r, a0);
            a0 = fmaf(ip[q0+4], w4, a0);
        }
        sH3[o][q0] = a0;
    }
    __syncthreads();
    // ---- head: 8 cols x 30 outs = 240; linW direct from global (L1-hot) ----
    if (tid < 240) {
        int q = tid / 30, j = tid % 30;
        int m = t0 + q;
        if (m < M) {
            float v = linb[j];
            #pragma unroll
            for (int oo = 0; oo < 32; oo++) v = fmaf(sH3[oo][q], linW[oo * 30 + j], v);
            if (j < 15) mu[((size_t)b * M + m) * 16 + j] = v;
            else        stdv[((size_t)b * M + m) * 16 + (j - 15)] = 0.1f + 0.9f * sigmoidf_(v);
        }
    }
}

// ---------------- Kernel 3: FinalLayer interpolation + output head ----------------
// grid: (ceil(ntar/8), nb), block 256 (32 m-groups x 8 t); mu/stdv row stride 16
__global__ void final_kernel(const float* __restrict__ x_out, const float* __restrict__ xg,
                             const float* __restrict__ int_sigma, const float* __restrict__ eps,
                             const float* __restrict__ mu, const float* __restrict__ stdv,
                             const float* __restrict__ loW, const float* __restrict__ lob,
                             float* __restrict__ out, int nb, int ntar, int M)
{
    __shared__ float red2[4][8][30];
    __shared__ float AB[8][30];
    int b = blockIdx.y;
    int tt = blockIdx.x * 8;
    int tid = threadIdx.x;
    int ti = tid & 7, mg = tid >> 3;
    int t = tt + ti;
    bool tv = (t < ntar);
    float xt[3];
    for (int c = 0; c < 3; c++) xt[c] = tv ? x_out[((size_t)b * ntar + t) * 3 + c] : 0.0f;
    float inv_isc[15];
    for (int k = 0; k < 15; k++) inv_isc[k] = 1.0f / (__expf(int_sigma[k]) + EPSF);
    float A[15], B[15];
    for (int k = 0; k < 15; k++) { A[k] = 0.0f; B[k] = 0.0f; }
    for (int m = mg; m < M; m += 32) {
        const float* gp = xg + (size_t)(b * M + m) * 3;
        float gv[3] = {gp[0], gp[1], gp[2]};
        const float* mup = mu + ((size_t)b * M + m) * 16;
        const float* sdp = stdv + ((size_t)b * M + m) * 16;
        float mv[15], sv[15];
        {
            float4 a0 = *(const float4*)(mup), a1 = *(const float4*)(mup + 4),
                   a2 = *(const float4*)(mup + 8);
            float4 s0 = *(const float4*)(sdp), s1 = *(const float4*)(sdp + 4),
                   s2 = *(const float4*)(sdp + 8);
            mv[0]=a0.x; mv[1]=a0.y; mv[2]=a0.z; mv[3]=a0.w;
            mv[4]=a1.x; mv[5]=a1.y; mv[6]=a1.z; mv[7]=a1.w;
            mv[8]=a2.x; mv[9]=a2.y; mv[10]=a2.z; mv[11]=a2.w;
            mv[12]=mup[12]; mv[13]=mup[13]; mv[14]=mup[14];
            sv[0]=s0.x; sv[1]=s0.y; sv[2]=s0.z; sv[3]=s0.w;
            sv[4]=s1.x; sv[5]=s1.y; sv[6]=s1.z; sv[7]=s1.w;
            sv[8]=s2.x; sv[9]=s2.y; sv[10]=s2.z; sv[11]=s2.w;
            sv[12]=sdp[12]; sv[13]=sdp[13]; sv[14]=sdp[14];
        }
        #pragma unroll
        for (int k = 0; k < 15; k++) {
            int c = k % 3;
            float d = (gv[c] - xt[c]) * inv_isc[k];
            float w = __expf(-0.5f * d * d);
            A[k] = fmaf(mv[k], w, A[k]);
            B[k] = fmaf(sv[k], w, B[k]);
        }
    }
    for (int mask = 8; mask <= 32; mask <<= 1) {
        for (int k = 0; k < 15; k++) {
            A[k] += __shfl_xor(A[k], mask, 64);
            B[k] += __shfl_xor(B[k], mask, 64);
        }
    }
    int lane = tid & 63, wv = tid >> 6;
    if (lane < 8) {
        for (int k = 0; k < 15; k++) { red2[wv][lane][k] = A[k]; red2[wv][lane][15 + k] = B[k]; }
    }
    __syncthreads();
    for (int idx = tid; idx < 240; idx += 256) {
        int t2 = idx / 30, v = idx % 30;
        AB[t2][v] = red2[0][t2][v] + red2[1][t2][v] + red2[2][t2][v] + red2[3][t2][v];
    }
    __syncthreads();
    if (tid < 192) {
        int t2 = tid / 24;
        int rem = tid % 24;
        int s = rem / 6, j = rem % 6;
        int tg = tt + t2;
        if (tg < ntar) {
            float val = lob[j];
            const float* ep = eps + ((size_t)s * nb + b) * 15;
            for (int k = 0; k < 15; k++) {
                float h = fmaf(ep[k], AB[t2][15 + k], AB[t2][k]);
                val = fmaf(h, loW[k * 6 + j], val);
            }
            if (j >= 3) val = fmaxf(val, 0.0f) + log1pf(__expf(-fabsf(val)));  // softplus
            out[(((size_t)s * nb + b) * ntar + tg) * 6 + j] = val;
        }
    }
}

extern "C" void kernel_launch(void* const* d_in, const int* in_sizes, int n_in,
                              void* d_out, int out_size, void* d_ws, size_t ws_size,
                              hipStream_t stream)
{
    const float* x         = (const float*)d_in[0];
    const float* y         = (const float*)d_in[1];
    const float* x_out     = (const float*)d_in[2];
    const float* x_grid    = (const float*)d_in[3];
    const float* eps_noise = (const float*)d_in[4];
    const float* enc_sigma = (const float*)d_in[5];
    const float* gW        = (const float*)d_in[6];
    const float* gb        = (const float*)d_in[7];
    const float* w1        = (const float*)d_in[8];
    const float* b1        = (const float*)d_in[9];
    const float* w2        = (const float*)d_in[10];
    const float* b2        = (const float*)d_in[11];
    const float* w3        = (const float*)d_in[12];
    const float* b3        = (const float*)d_in[13];
    const float* linW      = (const float*)d_in[14];
    const float* linb      = (const float*)d_in[15];
    const float* int_sigma = (const float*)d_in[16];
    const float* loW       = (const float*)d_in[17];
    const float* lob       = (const float*)d_in[18];
    float* out = (float*)d_out;

    const int NS = 4, C = 3, NBASIS = 5;
    int nb   = in_sizes[4] / (NS * C * NBASIS);       // eps_noise: (NS, nb, 15)
    int npts = in_sizes[0] / (nb * C);
    int ntar = in_sizes[2] / (nb * C);
    int M    = in_sizes[3] / (nb * C);

    float* rep_s = (float*)d_ws;                       // (nb, 16, M)
    float* mu    = rep_s + (size_t)nb * 16 * M;        // (nb, M, 16)  row stride 16
    float* stdv  = mu + (size_t)nb * M * 16;           // (nb, M, 16)

    if (npts == 2048) {
        enc_kernel_t<16><<<dim3((M + 7) / 8, nb), 1024, 0, stream>>>(
            x, y, x_grid, enc_sigma, gW, gb, rep_s, nb, M);
    } else {
        enc_kernel_g<<<dim3((M + 7) / 8, nb), 1024, 0, stream>>>(
            x, y, x_grid, enc_sigma, gW, gb, rep_s, nb, npts, M);
    }
    rho_kernel<<<dim3((M + 7) / 8, nb), 256, 0, stream>>>(
        rep_s, w1, b1, w2, b2, w3, b3, linW, linb, mu, stdv, nb, M);
    final_kernel<<<dim3((ntar + 7) / 8, nb), 256, 0, stream>>>(
        x_out, x_grid, int_sigma, eps_noise, mu, stdv, loW, lob, out, nb, ntar, M);
}